// Round 8
// baseline (238.821 us; speedup 1.0000x reference)
//
#include <hip/hip_runtime.h>
#include <hip/hip_bf16.h>
#include <stdint.h>

// Problem constants (fixed by reference): B=2, BEV=128, Q=16384, C=256,
// H=8, L=1, P=4, D=32. spatial_shapes == [[128,128]] (hardcoded).
#define Q_TOT 32768        // B*Q rows
#define CC 256
#define GRID_W 128
#define GRID_H 128

typedef __attribute__((ext_vector_type(8))) short short8;   // 8 bf16 = 4 VGPRs
typedef __attribute__((ext_vector_type(4))) float floatx4;  // MFMA accumulator

// ---------- helpers ----------
__device__ __forceinline__ ushort f2bf(float f) {
    union { float f; uint32_t u; } v; v.f = f;
    uint32_t r = (v.u + 0x7fffu + ((v.u >> 16) & 1u)) >> 16;   // RNE
    return (ushort)r;
}
// unpack 2 bf16 packed in a uint32 -> 2 floats (2 bit-ops)
__device__ __forceinline__ void bf2x2(uint32_t u, float& lo, float& hi) {
    union { uint32_t u; float f; } a, b;
    a.u = u << 16; b.u = u & 0xffff0000u;
    lo = a.f; hi = b.f;
}
// async global->LDS, 16B per lane. LDS dest must be wave-uniform.
__device__ __forceinline__ void async_load16(const void* g, void* l) {
    __builtin_amdgcn_global_load_lds(
        reinterpret_cast<const __attribute__((address_space(1))) uint32_t*>(
            reinterpret_cast<uintptr_t>(g)),
        reinterpret_cast<__attribute__((address_space(3))) uint32_t*>(
            reinterpret_cast<uintptr_t>(l)),
        16, 0, 0);
}

// ---------- prep: transposed bf16 weights ----------
__global__ __launch_bounds__(256)
void prep_weights(const float* __restrict__ Wv, const float* __restrict__ Wo,
                  const float* __restrict__ Woff, const float* __restrict__ Ww,
                  ushort* __restrict__ WvT, ushort* __restrict__ WoT,
                  ushort* __restrict__ WowT)
{
    int idx = blockIdx.x * blockDim.x + threadIdx.x;
    if (idx < 65536) {
        int n = idx >> 8, k = idx & 255;
        WvT[idx] = f2bf(Wv[k * 256 + n]);
    } else if (idx < 131072) {
        int t = idx - 65536; int n = t >> 8, k = t & 255;
        WoT[t] = f2bf(Wo[k * 256 + n]);
    } else if (idx < 155648) {
        int t = idx - 131072; int n = t >> 8, k = t & 255;
        float v = (n < 64) ? Woff[k * 64 + n] : Ww[k * 32 + (n - 64)];
        WowT[t] = f2bf(v);
    }
}

// ---------- bf16 MFMA GEMM: C[M,N] = A[M,K] @ Bt[N,K]^T + bias (+res) ----------
// 2-phase double-buffered pipeline; one barrier per K-step. XCD-swizzled grid
// (requires nwg % 8 == 0). CONV=1: A is fp32, reg-staged with bf16 conversion.
template <int BM, int BN, int WAVE_M, int WAVE_N, bool OUT_BF16, int CONV>
__global__ __launch_bounds__(256)
void gemm_bf16(const void* __restrict__ Av, const float* __restrict__ A2,
               const ushort* __restrict__ Bt,
               const float* __restrict__ bias, const float* __restrict__ res,
               void* __restrict__ Cout, int M, int N, int K)
{
    constexpr int TM = BM / WAVE_M / 16;   // MFMA row-tiles per wave
    constexpr int TN = BN / WAVE_N / 16;   // MFMA col-tiles per wave
    __shared__ __align__(16) ushort As[2][BM * 32];
    __shared__ __align__(16) ushort Bs[2][BN * 32];

    const int tid = threadIdx.x;
    const int lane = tid & 63;
    const int wave = tid >> 6;
    const int wm = wave / WAVE_N;
    const int wn = wave % WAVE_N;
    const int quad = lane >> 4;
    const int m16 = lane & 15;
    const int lrow = lane >> 2;          // staging: row within a 16-row group
    const int lkk = (lane & 3) * 8;      // staging: k element offset

    const int nwg = gridDim.x * gridDim.y;
    const int hw = blockIdx.y * gridDim.x + blockIdx.x;
    const int t = (hw & 7) * (nwg >> 3) + (hw >> 3);
    const int bx = t % gridDim.x;
    const int by = t / gridDim.x;

    const int row0 = by * BM;
    const int col0 = bx * BN;

    floatx4 acc[TM][TN] = {};

    auto stage = [&](int buf, int k0) {
        #pragma unroll
        for (int i = wave; i < BM / 16; i += 4) {
            const int r = row0 + i * 16 + lrow;
            if constexpr (CONV == 0) {
                const ushort* src = (const ushort*)Av + (size_t)r * K + (k0 + lkk);
                async_load16(src, &As[buf][i * 16 * 32]);
            } else {
                const float* src = (const float*)Av + (size_t)r * K + (k0 + lkk);
                float4 a0 = ((const float4*)src)[0];
                float4 a1 = ((const float4*)src)[1];
                if constexpr (CONV == 2) {
                    const float* s2 = A2 + (size_t)r * K + (k0 + lkk);
                    float4 b0 = ((const float4*)s2)[0];
                    float4 b1 = ((const float4*)s2)[1];
                    a0.x += b0.x; a0.y += b0.y; a0.z += b0.z; a0.w += b0.w;
                    a1.x += b1.x; a1.y += b1.y; a1.z += b1.z; a1.w += b1.w;
                }
                uint4 o;
                o.x = ((uint32_t)f2bf(a0.y) << 16) | f2bf(a0.x);
                o.y = ((uint32_t)f2bf(a0.w) << 16) | f2bf(a0.z);
                o.z = ((uint32_t)f2bf(a1.y) << 16) | f2bf(a1.x);
                o.w = ((uint32_t)f2bf(a1.w) << 16) | f2bf(a1.z);
                *(uint4*)&As[buf][i * 16 * 32 + lrow * 32 + lkk] = o;
            }
        }
        #pragma unroll
        for (int i = wave; i < BN / 16; i += 4) {
            const ushort* src = Bt + (size_t)(col0 + i * 16 + lrow) * K + (k0 + lkk);
            async_load16(src, &Bs[buf][i * 16 * 32]);
        }
    };

    stage(0, 0);
    __syncthreads();

    int cur = 0;
    for (int k0 = 0; k0 < K; k0 += 32) {
        if (k0 + 32 < K) stage(cur ^ 1, k0 + 32);

        short8 af[TM], bfr[TN];
        #pragma unroll
        for (int i = 0; i < TM; ++i)
            af[i] = *(const short8*)&As[cur][(wm * TM * 16 + i * 16 + m16) * 32 + quad * 8];
        #pragma unroll
        for (int j = 0; j < TN; ++j)
            bfr[j] = *(const short8*)&Bs[cur][(wn * TN * 16 + j * 16 + m16) * 32 + quad * 8];
        #pragma unroll
        for (int i = 0; i < TM; ++i)
            #pragma unroll
            for (int j = 0; j < TN; ++j)
                acc[i][j] = __builtin_amdgcn_mfma_f32_16x16x32_bf16(
                    af[i], bfr[j], acc[i][j], 0, 0, 0);

        __syncthreads();
        cur ^= 1;
    }

    #pragma unroll
    for (int i = 0; i < TM; ++i) {
        #pragma unroll
        for (int j = 0; j < TN; ++j) {
            const int gcol = col0 + wn * TN * 16 + j * 16 + m16;
            const float bb = bias[gcol];
            #pragma unroll
            for (int r = 0; r < 4; ++r) {
                const int grow = row0 + wm * TM * 16 + i * 16 + quad * 4 + r;
                float v = acc[i][j][r] + bb;
                if (res) v += res[(size_t)grow * N + gcol];
                if constexpr (OUT_BF16)
                    ((ushort*)Cout)[(size_t)grow * N + gcol] = f2bf(v);
                else
                    ((float*)Cout)[(size_t)grow * N + gcol] = v;
            }
        }
    }
}

// ---------- fused: ow-GEMM -> sampling -> out-GEMM, one block = 32 queries ----
// Barrier-light: B-operands (WowT/WoT, L2-resident) and phase-1 A (q+qp,
// converted in-register) read as MFMA fragments DIRECTLY from global.
// R8: phase-2 gathers restructured into a 16-deep load batch per head
// (addresses -> 16 loads in flight -> consume) to raise memory-level
// parallelism; everything else identical to the R7 measured-good kernel.
#define FBM 32
__global__ __launch_bounds__(256, 4)
void fused_attn(const float* __restrict__ query, const float* __restrict__ qpos,
                const ushort* __restrict__ WowT,   // [96][256] bf16
                const float* __restrict__ boff, const float* __restrict__ bw,
                const ushort* __restrict__ v2,     // (B,16384,256) bf16
                const float* __restrict__ ref,     // (B*Q,2)
                const ushort* __restrict__ WoT,    // [256][256] bf16
                const float* __restrict__ bo, const float* __restrict__ identity,
                float* __restrict__ out)
{
    __shared__ __align__(16) char smem[24576];
    ushort* samp = (ushort*)smem;              // [32][272] bf16  (phase 2->3)
    ushort* owl  = (ushort*)(smem + 17408);    // [32][100] bf16  (phase 1->2)

    const int tid  = threadIdx.x;
    const int lane = tid & 63;
    const int wave = tid >> 6;
    const int quad = lane >> 4;
    const int m16  = lane & 15;
    const int wm = wave >> 1;     // 0..1 (phase-1 row half)
    const int wn = wave & 1;      // 0..1 (phase-1 col half)
    const int q0 = blockIdx.x * FBM;

    // ---------------- phase 1: ow = (q+qp) @ WowT^T (no LDS, no barriers) -----
    floatx4 aow[3] = {};
    #pragma unroll 2
    for (int k0 = 0; k0 < 256; k0 += 32) {
        const size_t abase = (size_t)(q0 + wm * 16 + m16) * 256 + k0 + quad * 8;
        float4 a0 = ((const float4*)(query + abase))[0];
        float4 a1 = ((const float4*)(query + abase))[1];
        float4 b0 = ((const float4*)(qpos + abase))[0];
        float4 b1 = ((const float4*)(qpos + abase))[1];
        a0.x += b0.x; a0.y += b0.y; a0.z += b0.z; a0.w += b0.w;
        a1.x += b1.x; a1.y += b1.y; a1.z += b1.z; a1.w += b1.w;
        union { short8 s; uint32_t u[4]; } ua;
        ua.u[0] = ((uint32_t)f2bf(a0.y) << 16) | f2bf(a0.x);
        ua.u[1] = ((uint32_t)f2bf(a0.w) << 16) | f2bf(a0.z);
        ua.u[2] = ((uint32_t)f2bf(a1.y) << 16) | f2bf(a1.x);
        ua.u[3] = ((uint32_t)f2bf(a1.w) << 16) | f2bf(a1.z);
        short8 bfw[3];
        #pragma unroll
        for (int j = 0; j < 3; ++j)
            bfw[j] = *(const short8*)(WowT +
                (size_t)(wn * 48 + j * 16 + m16) * 256 + k0 + quad * 8);
        #pragma unroll
        for (int j = 0; j < 3; ++j)
            aow[j] = __builtin_amdgcn_mfma_f32_16x16x32_bf16(
                ua.s, bfw[j], aow[j], 0, 0, 0);
    }
    // epilogue -> owl (bf16), bias from boff|bw
    #pragma unroll
    for (int j = 0; j < 3; ++j) {
        const int col = wn * 48 + j * 16 + m16;
        const float bb = (col < 64) ? boff[col] : bw[col - 64];
        #pragma unroll
        for (int r = 0; r < 4; ++r)
            owl[(wm * 16 + quad * 4 + r) * 100 + col] = f2bf(aow[j][r] + bb);
    }
    __syncthreads();

    // ---------------- phase 2: softmax + bilinear sampling ----------------
    {
        const int ql = tid >> 3;          // 0..31 query within block
        const int hh = (tid >> 2) & 1;    // head half: h = hh*4 + hi
        const int dg = tid & 3;           // channel group (8 ch)
        const int qg = q0 + ql;
        const int bb2 = qg >> 14;
        const float rx = ref[(size_t)qg * 2 + 0] * (float)GRID_W;
        const float ry = ref[(size_t)qg * 2 + 1] * (float)GRID_H;
        const ushort* vbase = v2 + (size_t)bb2 * 16384 * 256 + dg * 8;
        const uint32_t* owr = (const uint32_t*)&owl[ql * 100];

        // NOT unrolled across heads: keeps the 16-deep load batch at ~64 VGPRs.
        #pragma unroll 1
        for (int hi = 0; hi < 4; ++hi) {
            const int h = hh * 4 + hi;
            float w0, w1, w2, w3;
            bf2x2(owr[32 + h * 2 + 0], w0, w1);
            bf2x2(owr[32 + h * 2 + 1], w2, w3);
            const float mx = fmaxf(fmaxf(w0, w1), fmaxf(w2, w3));
            const float e0 = __expf(w0 - mx), e1 = __expf(w1 - mx);
            const float e2 = __expf(w2 - mx), e3 = __expf(w3 - mx);
            const float inv = 1.f / (e0 + e1 + e2 + e3);
            const float aw[4] = {e0 * inv, e1 * inv, e2 * inv, e3 * inv};

            float offs[8];
            bf2x2(owr[h * 4 + 0], offs[0], offs[1]);
            bf2x2(owr[h * 4 + 1], offs[2], offs[3]);
            bf2x2(owr[h * 4 + 2], offs[4], offs[5]);
            bf2x2(owr[h * 4 + 3], offs[6], offs[7]);

            const ushort* vh = vbase + h * 32;

            // pass 1: all 16 corner offsets + weights (static unroll -> regs)
            uint32_t idx[16];
            float cw[16];
            #pragma unroll
            for (int p = 0; p < 4; ++p) {
                const float x = rx + offs[p * 2 + 0] - 0.5f;
                const float y = ry + offs[p * 2 + 1] - 0.5f;
                const float x0f = floorf(x), y0f = floorf(y);
                const float dx = x - x0f, dy = y - y0f;
                const int x0 = (int)x0f, y0 = (int)y0f;
                const int x1 = x0 + 1, y1 = y0 + 1;
                const float vx0 = (x0 >= 0 && x0 < GRID_W) ? 1.f : 0.f;
                const float vx1 = (x1 >= 0 && x1 < GRID_W) ? 1.f : 0.f;
                const float vy0 = (y0 >= 0 && y0 < GRID_H) ? 1.f : 0.f;
                const float vy1 = (y1 >= 0 && y1 < GRID_H) ? 1.f : 0.f;
                const int xc0 = min(max(x0, 0), GRID_W - 1);
                const int xc1 = min(max(x1, 0), GRID_W - 1);
                const int yc0 = min(max(y0, 0), GRID_H - 1);
                const int yc1 = min(max(y1, 0), GRID_H - 1);
                cw[p * 4 + 0] = aw[p] * (1.f - dx) * (1.f - dy) * vx0 * vy0;
                cw[p * 4 + 1] = aw[p] * dx * (1.f - dy) * vx1 * vy0;
                cw[p * 4 + 2] = aw[p] * (1.f - dx) * dy * vx0 * vy1;
                cw[p * 4 + 3] = aw[p] * dx * dy * vx1 * vy1;
                const int base0 = yc0 * GRID_W, base1 = yc1 * GRID_W;
                idx[p * 4 + 0] = (uint32_t)(base0 + xc0) * 256u;
                idx[p * 4 + 1] = (uint32_t)(base0 + xc1) * 256u;
                idx[p * 4 + 2] = (uint32_t)(base1 + xc0) * 256u;
                idx[p * 4 + 3] = (uint32_t)(base1 + xc1) * 256u;
            }
            // pass 2: issue all 16 loads (16 in flight per thread)
            uint4 r[16];
            #pragma unroll
            for (int c = 0; c < 16; ++c)
                r[c] = *(const uint4*)(vh + idx[c]);
            // pass 3: consume (same FMA order as before: p-major, corner order
            // 00,10,01,11 -> bit-identical accumulation)
            float acc8[8] = {};
            #pragma unroll
            for (int c = 0; c < 16; ++c) {
                float lo, hi2;
                bf2x2(r[c].x, lo, hi2); acc8[0] += cw[c] * lo; acc8[1] += cw[c] * hi2;
                bf2x2(r[c].y, lo, hi2); acc8[2] += cw[c] * lo; acc8[3] += cw[c] * hi2;
                bf2x2(r[c].z, lo, hi2); acc8[4] += cw[c] * lo; acc8[5] += cw[c] * hi2;
                bf2x2(r[c].w, lo, hi2); acc8[6] += cw[c] * lo; acc8[7] += cw[c] * hi2;
            }
            uint4 o;
            o.x = ((uint32_t)f2bf(acc8[1]) << 16) | f2bf(acc8[0]);
            o.y = ((uint32_t)f2bf(acc8[3]) << 16) | f2bf(acc8[2]);
            o.z = ((uint32_t)f2bf(acc8[5]) << 16) | f2bf(acc8[4]);
            o.w = ((uint32_t)f2bf(acc8[7]) << 16) | f2bf(acc8[6]);
            *(uint4*)&samp[ql * 272 + h * 32 + dg * 8] = o;
        }
    }
    __syncthreads();   // samp ready

    // ---------------- phase 3: out = samp @ WoT^T (+bo +identity) -------------
    // Identity prefetched into registers BEFORE the MFMA loop: its HBM latency
    // hides under 8 K-steps of fragment loads + MFMA.
    float idv[2][4][4];
    #pragma unroll
    for (int i = 0; i < 2; ++i)
        #pragma unroll
        for (int j = 0; j < 4; ++j)
            #pragma unroll
            for (int r = 0; r < 4; ++r)
                idv[i][j][r] = identity[
                    (size_t)(q0 + i * 16 + quad * 4 + r) * 256 +
                    wave * 64 + j * 16 + m16];

    floatx4 acc[2][4] = {};
    #pragma unroll 2
    for (int ks = 0; ks < 8; ++ks) {
        short8 af2[2], bfr[4];
        #pragma unroll
        for (int i = 0; i < 2; ++i)
            af2[i] = *(const short8*)&samp[(i * 16 + m16) * 272 + ks * 32 + quad * 8];
        #pragma unroll
        for (int j = 0; j < 4; ++j)
            bfr[j] = *(const short8*)(WoT +
                (size_t)(wave * 64 + j * 16 + m16) * 256 + ks * 32 + quad * 8);
        #pragma unroll
        for (int i = 0; i < 2; ++i)
            #pragma unroll
            for (int j = 0; j < 4; ++j)
                acc[i][j] = __builtin_amdgcn_mfma_f32_16x16x32_bf16(
                    af2[i], bfr[j], acc[i][j], 0, 0, 0);
    }

    #pragma unroll
    for (int i = 0; i < 2; ++i)
        #pragma unroll
        for (int j = 0; j < 4; ++j) {
            const int gcol = wave * 64 + j * 16 + m16;
            const float bb = bo[gcol];
            #pragma unroll
            for (int r = 0; r < 4; ++r) {
                const int grow = q0 + i * 16 + quad * 4 + r;
                out[(size_t)grow * 256 + gcol] = acc[i][j][r] + bb + idv[i][j][r];
            }
        }
}

extern "C" void kernel_launch(void* const* d_in, const int* in_sizes, int n_in,
                              void* d_out, int out_size, void* d_ws, size_t ws_size,
                              hipStream_t stream) {
    const float* query     = (const float*)d_in[0];
    const float* value     = (const float*)d_in[1];
    const float* identity  = (const float*)d_in[2];
    const float* query_pos = (const float*)d_in[3];
    const float* refpts    = (const float*)d_in[4];
    const float* Wv   = (const float*)d_in[7];
    const float* bv   = (const float*)d_in[8];
    const float* Woff = (const float*)d_in[9];
    const float* boff = (const float*)d_in[10];
    const float* Ww   = (const float*)d_in[11];
    const float* bw   = (const float*)d_in[12];
    const float* Wo   = (const float*)d_in[13];
    const float* bo   = (const float*)d_in[14];
    float* out = (float*)d_out;

    char* ws = (char*)d_ws;
    ushort* v2_bf = (ushort*)(ws);                 // 16,777,216 B
    ushort* WvT   = (ushort*)(ws + 16777216);      //    131,072 B
    ushort* WoT   = (ushort*)(ws + 16908288);      //    131,072 B
    ushort* WowT  = (ushort*)(ws + 17039360);      //     49,152 B

    // 1) transposed bf16 weights
    prep_weights<<<608, 256, 0, stream>>>(Wv, Wo, Woff, Ww, WvT, WoT, WowT);
    // 2) v2 = value @ Wv + bv  (fp32 A converted in staging, bf16 out)
    gemm_bf16<128, 64, 2, 2, true, 1><<<dim3(4, 256), 256, 0, stream>>>(
        value, nullptr, WvT, bv, nullptr, v2_bf, Q_TOT, 256, 256);
    // 3) fused ow-GEMM + sampling + out-GEMM (+bo +identity)
    fused_attn<<<dim3(Q_TOT / FBM), 256, 0, stream>>>(
        query, query_pos, WowT, boff, bw, v2_bf, refpts, WoT, bo, identity, out);
}

// Round 9
// 237.688 us; speedup vs baseline: 1.0048x; 1.0048x over previous
//
#include <hip/hip_runtime.h>
#include <hip/hip_bf16.h>
#include <stdint.h>

// Problem constants (fixed by reference): B=2, BEV=128, Q=16384, C=256,
// H=8, L=1, P=4, D=32. spatial_shapes == [[128,128]] (hardcoded).
#define Q_TOT 32768        // B*Q rows
#define CC 256
#define GRID_W 128
#define GRID_H 128

typedef __attribute__((ext_vector_type(8))) short short8;   // 8 bf16 = 4 VGPRs
typedef __attribute__((ext_vector_type(4))) float floatx4;  // MFMA accumulator

// ---------- helpers ----------
__device__ __forceinline__ ushort f2bf(float f) {
    union { float f; uint32_t u; } v; v.f = f;
    uint32_t r = (v.u + 0x7fffu + ((v.u >> 16) & 1u)) >> 16;   // RNE
    return (ushort)r;
}
// unpack 2 bf16 packed in a uint32 -> 2 floats (2 bit-ops)
__device__ __forceinline__ void bf2x2(uint32_t u, float& lo, float& hi) {
    union { uint32_t u; float f; } a, b;
    a.u = u << 16; b.u = u & 0xffff0000u;
    lo = a.f; hi = b.f;
}
// async global->LDS, 16B per lane. LDS dest must be wave-uniform.
__device__ __forceinline__ void async_load16(const void* g, void* l) {
    __builtin_amdgcn_global_load_lds(
        reinterpret_cast<const __attribute__((address_space(1))) uint32_t*>(
            reinterpret_cast<uintptr_t>(g)),
        reinterpret_cast<__attribute__((address_space(3))) uint32_t*>(
            reinterpret_cast<uintptr_t>(l)),
        16, 0, 0);
}

// ---------- prep: transposed bf16 weights ----------
__global__ __launch_bounds__(256)
void prep_weights(const float* __restrict__ Wv, const float* __restrict__ Wo,
                  const float* __restrict__ Woff, const float* __restrict__ Ww,
                  ushort* __restrict__ WvT, ushort* __restrict__ WoT,
                  ushort* __restrict__ WowT)
{
    int idx = blockIdx.x * blockDim.x + threadIdx.x;
    if (idx < 65536) {
        int n = idx >> 8, k = idx & 255;
        WvT[idx] = f2bf(Wv[k * 256 + n]);
    } else if (idx < 131072) {
        int t = idx - 65536; int n = t >> 8, k = t & 255;
        WoT[t] = f2bf(Wo[k * 256 + n]);
    } else if (idx < 155648) {
        int t = idx - 131072; int n = t >> 8, k = t & 255;
        float v = (n < 64) ? Woff[k * 64 + n] : Ww[k * 32 + (n - 64)];
        WowT[t] = f2bf(v);
    }
}

// ---------- bf16 MFMA GEMM: C[M,N] = A[M,K] @ Bt[N,K]^T + bias (+res) ----------
// 2-phase double-buffered pipeline; one barrier per K-step. XCD-swizzled grid
// (requires nwg % 8 == 0). CONV=1: A is fp32, reg-staged with bf16 conversion.
template <int BM, int BN, int WAVE_M, int WAVE_N, bool OUT_BF16, int CONV>
__global__ __launch_bounds__(256)
void gemm_bf16(const void* __restrict__ Av, const float* __restrict__ A2,
               const ushort* __restrict__ Bt,
               const float* __restrict__ bias, const float* __restrict__ res,
               void* __restrict__ Cout, int M, int N, int K)
{
    constexpr int TM = BM / WAVE_M / 16;   // MFMA row-tiles per wave
    constexpr int TN = BN / WAVE_N / 16;   // MFMA col-tiles per wave
    __shared__ __align__(16) ushort As[2][BM * 32];
    __shared__ __align__(16) ushort Bs[2][BN * 32];

    const int tid = threadIdx.x;
    const int lane = tid & 63;
    const int wave = tid >> 6;
    const int wm = wave / WAVE_N;
    const int wn = wave % WAVE_N;
    const int quad = lane >> 4;
    const int m16 = lane & 15;
    const int lrow = lane >> 2;          // staging: row within a 16-row group
    const int lkk = (lane & 3) * 8;      // staging: k element offset

    const int nwg = gridDim.x * gridDim.y;
    const int hw = blockIdx.y * gridDim.x + blockIdx.x;
    const int t = (hw & 7) * (nwg >> 3) + (hw >> 3);
    const int bx = t % gridDim.x;
    const int by = t / gridDim.x;

    const int row0 = by * BM;
    const int col0 = bx * BN;

    floatx4 acc[TM][TN] = {};

    auto stage = [&](int buf, int k0) {
        #pragma unroll
        for (int i = wave; i < BM / 16; i += 4) {
            const int r = row0 + i * 16 + lrow;
            if constexpr (CONV == 0) {
                const ushort* src = (const ushort*)Av + (size_t)r * K + (k0 + lkk);
                async_load16(src, &As[buf][i * 16 * 32]);
            } else {
                const float* src = (const float*)Av + (size_t)r * K + (k0 + lkk);
                float4 a0 = ((const float4*)src)[0];
                float4 a1 = ((const float4*)src)[1];
                if constexpr (CONV == 2) {
                    const float* s2 = A2 + (size_t)r * K + (k0 + lkk);
                    float4 b0 = ((const float4*)s2)[0];
                    float4 b1 = ((const float4*)s2)[1];
                    a0.x += b0.x; a0.y += b0.y; a0.z += b0.z; a0.w += b0.w;
                    a1.x += b1.x; a1.y += b1.y; a1.z += b1.z; a1.w += b1.w;
                }
                uint4 o;
                o.x = ((uint32_t)f2bf(a0.y) << 16) | f2bf(a0.x);
                o.y = ((uint32_t)f2bf(a0.w) << 16) | f2bf(a0.z);
                o.z = ((uint32_t)f2bf(a1.y) << 16) | f2bf(a1.x);
                o.w = ((uint32_t)f2bf(a1.w) << 16) | f2bf(a1.z);
                *(uint4*)&As[buf][i * 16 * 32 + lrow * 32 + lkk] = o;
            }
        }
        #pragma unroll
        for (int i = wave; i < BN / 16; i += 4) {
            const ushort* src = Bt + (size_t)(col0 + i * 16 + lrow) * K + (k0 + lkk);
            async_load16(src, &Bs[buf][i * 16 * 32]);
        }
    };

    stage(0, 0);
    __syncthreads();

    int cur = 0;
    for (int k0 = 0; k0 < K; k0 += 32) {
        if (k0 + 32 < K) stage(cur ^ 1, k0 + 32);

        short8 af[TM], bfr[TN];
        #pragma unroll
        for (int i = 0; i < TM; ++i)
            af[i] = *(const short8*)&As[cur][(wm * TM * 16 + i * 16 + m16) * 32 + quad * 8];
        #pragma unroll
        for (int j = 0; j < TN; ++j)
            bfr[j] = *(const short8*)&Bs[cur][(wn * TN * 16 + j * 16 + m16) * 32 + quad * 8];
        #pragma unroll
        for (int i = 0; i < TM; ++i)
            #pragma unroll
            for (int j = 0; j < TN; ++j)
                acc[i][j] = __builtin_amdgcn_mfma_f32_16x16x32_bf16(
                    af[i], bfr[j], acc[i][j], 0, 0, 0);

        __syncthreads();
        cur ^= 1;
    }

    #pragma unroll
    for (int i = 0; i < TM; ++i) {
        #pragma unroll
        for (int j = 0; j < TN; ++j) {
            const int gcol = col0 + wn * TN * 16 + j * 16 + m16;
            const float bb = bias[gcol];
            #pragma unroll
            for (int r = 0; r < 4; ++r) {
                const int grow = row0 + wm * TM * 16 + i * 16 + quad * 4 + r;
                float v = acc[i][j][r] + bb;
                if (res) v += res[(size_t)grow * N + gcol];
                if constexpr (OUT_BF16)
                    ((ushort*)Cout)[(size_t)grow * N + gcol] = f2bf(v);
                else
                    ((float*)Cout)[(size_t)grow * N + gcol] = v;
            }
        }
    }
}

// ---------- fused: ow-GEMM -> sampling -> out-GEMM, one block = 32 queries ----
// Barrier-light: B-operands (WowT/WoT, L2-resident) and phase-1 A (q+qp,
// converted in-register) read as MFMA fragments DIRECTLY from global.
// R9: phase-2 load batch PINNED with sched_barrier(0) so the compiler cannot
// re-serialize it (R8's VGPR=60 showed the batch was undone). 16 gathers in
// flight per thread before any consume.
#define FBM 32
__global__ __launch_bounds__(256, 4)
void fused_attn(const float* __restrict__ query, const float* __restrict__ qpos,
                const ushort* __restrict__ WowT,   // [96][256] bf16
                const float* __restrict__ boff, const float* __restrict__ bw,
                const ushort* __restrict__ v2,     // (B,16384,256) bf16
                const float* __restrict__ ref,     // (B*Q,2)
                const ushort* __restrict__ WoT,    // [256][256] bf16
                const float* __restrict__ bo, const float* __restrict__ identity,
                float* __restrict__ out)
{
    __shared__ __align__(16) char smem[24576];
    ushort* samp = (ushort*)smem;              // [32][272] bf16  (phase 2->3)
    ushort* owl  = (ushort*)(smem + 17408);    // [32][100] bf16  (phase 1->2)

    const int tid  = threadIdx.x;
    const int lane = tid & 63;
    const int wave = tid >> 6;
    const int quad = lane >> 4;
    const int m16  = lane & 15;
    const int wm = wave >> 1;     // 0..1 (phase-1 row half)
    const int wn = wave & 1;      // 0..1 (phase-1 col half)
    const int q0 = blockIdx.x * FBM;

    // ---------------- phase 1: ow = (q+qp) @ WowT^T (no LDS, no barriers) -----
    floatx4 aow[3] = {};
    #pragma unroll 2
    for (int k0 = 0; k0 < 256; k0 += 32) {
        const size_t abase = (size_t)(q0 + wm * 16 + m16) * 256 + k0 + quad * 8;
        float4 a0 = ((const float4*)(query + abase))[0];
        float4 a1 = ((const float4*)(query + abase))[1];
        float4 b0 = ((const float4*)(qpos + abase))[0];
        float4 b1 = ((const float4*)(qpos + abase))[1];
        a0.x += b0.x; a0.y += b0.y; a0.z += b0.z; a0.w += b0.w;
        a1.x += b1.x; a1.y += b1.y; a1.z += b1.z; a1.w += b1.w;
        union { short8 s; uint32_t u[4]; } ua;
        ua.u[0] = ((uint32_t)f2bf(a0.y) << 16) | f2bf(a0.x);
        ua.u[1] = ((uint32_t)f2bf(a0.w) << 16) | f2bf(a0.z);
        ua.u[2] = ((uint32_t)f2bf(a1.y) << 16) | f2bf(a1.x);
        ua.u[3] = ((uint32_t)f2bf(a1.w) << 16) | f2bf(a1.z);
        short8 bfw[3];
        #pragma unroll
        for (int j = 0; j < 3; ++j)
            bfw[j] = *(const short8*)(WowT +
                (size_t)(wn * 48 + j * 16 + m16) * 256 + k0 + quad * 8);
        #pragma unroll
        for (int j = 0; j < 3; ++j)
            aow[j] = __builtin_amdgcn_mfma_f32_16x16x32_bf16(
                ua.s, bfw[j], aow[j], 0, 0, 0);
    }
    // epilogue -> owl (bf16), bias from boff|bw
    #pragma unroll
    for (int j = 0; j < 3; ++j) {
        const int col = wn * 48 + j * 16 + m16;
        const float bb = (col < 64) ? boff[col] : bw[col - 64];
        #pragma unroll
        for (int r = 0; r < 4; ++r)
            owl[(wm * 16 + quad * 4 + r) * 100 + col] = f2bf(aow[j][r] + bb);
    }
    __syncthreads();

    // ---------------- phase 2: softmax + bilinear sampling ----------------
    {
        const int ql = tid >> 3;          // 0..31 query within block
        const int hh = (tid >> 2) & 1;    // head half: h = hh*4 + hi
        const int dg = tid & 3;           // channel group (8 ch)
        const int qg = q0 + ql;
        const int bb2 = qg >> 14;
        const float rx = ref[(size_t)qg * 2 + 0] * (float)GRID_W;
        const float ry = ref[(size_t)qg * 2 + 1] * (float)GRID_H;
        const ushort* vbase = v2 + (size_t)bb2 * 16384 * 256 + dg * 8;
        const uint32_t* owr = (const uint32_t*)&owl[ql * 100];

        // NOT unrolled across heads: keeps the 16-deep load batch at ~64 VGPRs.
        #pragma unroll 1
        for (int hi = 0; hi < 4; ++hi) {
            const int h = hh * 4 + hi;
            float w0, w1, w2, w3;
            bf2x2(owr[32 + h * 2 + 0], w0, w1);
            bf2x2(owr[32 + h * 2 + 1], w2, w3);
            const float mx = fmaxf(fmaxf(w0, w1), fmaxf(w2, w3));
            const float e0 = __expf(w0 - mx), e1 = __expf(w1 - mx);
            const float e2 = __expf(w2 - mx), e3 = __expf(w3 - mx);
            const float inv = 1.f / (e0 + e1 + e2 + e3);
            const float aw[4] = {e0 * inv, e1 * inv, e2 * inv, e3 * inv};

            float offs[8];
            bf2x2(owr[h * 4 + 0], offs[0], offs[1]);
            bf2x2(owr[h * 4 + 1], offs[2], offs[3]);
            bf2x2(owr[h * 4 + 2], offs[4], offs[5]);
            bf2x2(owr[h * 4 + 3], offs[6], offs[7]);

            const ushort* vh = vbase + h * 32;

            // pass 1: all 16 corner offsets + weights (static unroll -> regs)
            uint32_t idx[16];
            float cw[16];
            #pragma unroll
            for (int p = 0; p < 4; ++p) {
                const float x = rx + offs[p * 2 + 0] - 0.5f;
                const float y = ry + offs[p * 2 + 1] - 0.5f;
                const float x0f = floorf(x), y0f = floorf(y);
                const float dx = x - x0f, dy = y - y0f;
                const int x0 = (int)x0f, y0 = (int)y0f;
                const int x1 = x0 + 1, y1 = y0 + 1;
                const float vx0 = (x0 >= 0 && x0 < GRID_W) ? 1.f : 0.f;
                const float vx1 = (x1 >= 0 && x1 < GRID_W) ? 1.f : 0.f;
                const float vy0 = (y0 >= 0 && y0 < GRID_H) ? 1.f : 0.f;
                const float vy1 = (y1 >= 0 && y1 < GRID_H) ? 1.f : 0.f;
                const int xc0 = min(max(x0, 0), GRID_W - 1);
                const int xc1 = min(max(x1, 0), GRID_W - 1);
                const int yc0 = min(max(y0, 0), GRID_H - 1);
                const int yc1 = min(max(y1, 0), GRID_H - 1);
                cw[p * 4 + 0] = aw[p] * (1.f - dx) * (1.f - dy) * vx0 * vy0;
                cw[p * 4 + 1] = aw[p] * dx * (1.f - dy) * vx1 * vy0;
                cw[p * 4 + 2] = aw[p] * (1.f - dx) * dy * vx0 * vy1;
                cw[p * 4 + 3] = aw[p] * dx * dy * vx1 * vy1;
                const int base0 = yc0 * GRID_W, base1 = yc1 * GRID_W;
                idx[p * 4 + 0] = (uint32_t)(base0 + xc0) * 256u;
                idx[p * 4 + 1] = (uint32_t)(base0 + xc1) * 256u;
                idx[p * 4 + 2] = (uint32_t)(base1 + xc0) * 256u;
                idx[p * 4 + 3] = (uint32_t)(base1 + xc1) * 256u;
            }
            // pass 2: issue all 16 loads
            uint4 r[16];
            #pragma unroll
            for (int c = 0; c < 16; ++c)
                r[c] = *(const uint4*)(vh + idx[c]);
            // Compile-time scheduling fence: compiler may NOT sink these loads
            // toward their uses (R8 showed it re-serializes to save VGPRs).
            // All 16 loads are issued before any consume -> 16 outstanding.
            __builtin_amdgcn_sched_barrier(0);
            // pass 3: consume (same FMA order as before -> bit-identical)
            float acc8[8] = {};
            #pragma unroll
            for (int c = 0; c < 16; ++c) {
                float lo, hi2;
                bf2x2(r[c].x, lo, hi2); acc8[0] += cw[c] * lo; acc8[1] += cw[c] * hi2;
                bf2x2(r[c].y, lo, hi2); acc8[2] += cw[c] * lo; acc8[3] += cw[c] * hi2;
                bf2x2(r[c].z, lo, hi2); acc8[4] += cw[c] * lo; acc8[5] += cw[c] * hi2;
                bf2x2(r[c].w, lo, hi2); acc8[6] += cw[c] * lo; acc8[7] += cw[c] * hi2;
            }
            uint4 o;
            o.x = ((uint32_t)f2bf(acc8[1]) << 16) | f2bf(acc8[0]);
            o.y = ((uint32_t)f2bf(acc8[3]) << 16) | f2bf(acc8[2]);
            o.z = ((uint32_t)f2bf(acc8[5]) << 16) | f2bf(acc8[4]);
            o.w = ((uint32_t)f2bf(acc8[7]) << 16) | f2bf(acc8[6]);
            *(uint4*)&samp[ql * 272 + h * 32 + dg * 8] = o;
        }
    }
    __syncthreads();   // samp ready

    // ---------------- phase 3: out = samp @ WoT^T (+bo +identity) -------------
    // Identity prefetched into registers BEFORE the MFMA loop: its HBM latency
    // hides under 8 K-steps of fragment loads + MFMA.
    float idv[2][4][4];
    #pragma unroll
    for (int i = 0; i < 2; ++i)
        #pragma unroll
        for (int j = 0; j < 4; ++j)
            #pragma unroll
            for (int r = 0; r < 4; ++r)
                idv[i][j][r] = identity[
                    (size_t)(q0 + i * 16 + quad * 4 + r) * 256 +
                    wave * 64 + j * 16 + m16];

    floatx4 acc[2][4] = {};
    #pragma unroll 2
    for (int ks = 0; ks < 8; ++ks) {
        short8 af2[2], bfr[4];
        #pragma unroll
        for (int i = 0; i < 2; ++i)
            af2[i] = *(const short8*)&samp[(i * 16 + m16) * 272 + ks * 32 + quad * 8];
        #pragma unroll
        for (int j = 0; j < 4; ++j)
            bfr[j] = *(const short8*)(WoT +
                (size_t)(wave * 64 + j * 16 + m16) * 256 + ks * 32 + quad * 8);
        #pragma unroll
        for (int i = 0; i < 2; ++i)
            #pragma unroll
            for (int j = 0; j < 4; ++j)
                acc[i][j] = __builtin_amdgcn_mfma_f32_16x16x32_bf16(
                    af2[i], bfr[j], acc[i][j], 0, 0, 0);
    }

    #pragma unroll
    for (int i = 0; i < 2; ++i)
        #pragma unroll
        for (int j = 0; j < 4; ++j) {
            const int gcol = wave * 64 + j * 16 + m16;
            const float bb = bo[gcol];
            #pragma unroll
            for (int r = 0; r < 4; ++r) {
                const int grow = q0 + i * 16 + quad * 4 + r;
                out[(size_t)grow * 256 + gcol] = acc[i][j][r] + bb + idv[i][j][r];
            }
        }
}

extern "C" void kernel_launch(void* const* d_in, const int* in_sizes, int n_in,
                              void* d_out, int out_size, void* d_ws, size_t ws_size,
                              hipStream_t stream) {
    const float* query     = (const float*)d_in[0];
    const float* value     = (const float*)d_in[1];
    const float* identity  = (const float*)d_in[2];
    const float* query_pos = (const float*)d_in[3];
    const float* refpts    = (const float*)d_in[4];
    const float* Wv   = (const float*)d_in[7];
    const float* bv   = (const float*)d_in[8];
    const float* Woff = (const float*)d_in[9];
    const float* boff = (const float*)d_in[10];
    const float* Ww   = (const float*)d_in[11];
    const float* bw   = (const float*)d_in[12];
    const float* Wo   = (const float*)d_in[13];
    const float* bo   = (const float*)d_in[14];
    float* out = (float*)d_out;

    char* ws = (char*)d_ws;
    ushort* v2_bf = (ushort*)(ws);                 // 16,777,216 B
    ushort* WvT   = (ushort*)(ws + 16777216);      //    131,072 B
    ushort* WoT   = (ushort*)(ws + 16908288);      //    131,072 B
    ushort* WowT  = (ushort*)(ws + 17039360);      //     49,152 B

    // 1) transposed bf16 weights
    prep_weights<<<608, 256, 0, stream>>>(Wv, Wo, Woff, Ww, WvT, WoT, WowT);
    // 2) v2 = value @ Wv + bv  (fp32 A converted in staging, bf16 out)
    gemm_bf16<128, 64, 2, 2, true, 1><<<dim3(4, 256), 256, 0, stream>>>(
        value, nullptr, WvT, bv, nullptr, v2_bf, Q_TOT, 256, 256);
    // 3) fused ow-GEMM + sampling + out-GEMM (+bo +identity)
    fused_attn<<<dim3(Q_TOT / FBM), 256, 0, stream>>>(
        query, query_pos, WowT, boff, bw, v2_bf, refpts, WoT, bo, identity, out);
}